// Round 1
// baseline (441.379 us; speedup 1.0000x reference)
//
#include <hip/hip_runtime.h>

// Jacobi iteration, 5 steps, cross-stencil (5-point FD second derivative per axis,
// center folded into diagonal). B=16, H=W=1024, fp32.
// new[i,j] = d_inv * (rhs[i,j] - cr[i,j])   for 2<=i<H-2, 2<=j<W-2
// cr = cH2*(g[i-2,j]+g[i+2,j]) + cH1*(g[i-1,j]+g[i+1,j])
//    + cW2*(g[i,j-2]+g[i,j+2]) + cW1*(g[i,j-1]+g[i,j+1])
// boundary ring (width 2) copied through unchanged.
// cH1 = (4/3)*p0, cH2 = (-1/12)*p0, p0=(1/dx[b,0])^2 (rows); cW* likewise with p1.
// d_inv = 1 / (-2.5*(p0+p1)).

#define HH 1024
#define WW 1024
#define NB 16

__global__ __launch_bounds__(256) void jacobi_step(
    const float* __restrict__ src, const float* __restrict__ rhs,
    const float* __restrict__ dx, float* __restrict__ dst)
{
    const int i = (int)blockIdx.x;           // row
    const int b = (int)blockIdx.y;           // batch
    const int j = (int)threadIdx.x * 4;      // first of 4 cols
    const size_t base = ((size_t)b * HH + (size_t)i) * WW;

    // frozen boundary rows: straight copy
    if (i < 2 || i >= HH - 2) {
        const float4 v = *(const float4*)(src + base + j);
        *(float4*)(dst + base + j) = v;
        return;
    }

    // per-batch constants (cheap, L1-cached)
    const float dx0 = dx[2 * b + 0];
    const float dx1 = dx[2 * b + 1];
    const float t0 = 1.0f / dx0, t1 = 1.0f / dx1;
    const float p0 = t0 * t0, p1 = t1 * t1;          // (1/dx)^order, order=2
    const float cH1 = (4.0f / 3.0f) * p0, cH2 = (-1.0f / 12.0f) * p0;
    const float cW1 = (4.0f / 3.0f) * p1, cW2 = (-1.0f / 12.0f) * p1;
    const float d_inv = 1.0f / (-2.5f * (p0 + p1));

    // vertical taps: 4 aligned float4 row loads
    const float4 rm2 = *(const float4*)(src + base - 2 * WW + j);
    const float4 rm1 = *(const float4*)(src + base - 1 * WW + j);
    const float4 c4  = *(const float4*)(src + base + j);
    const float4 rp1 = *(const float4*)(src + base + 1 * WW + j);
    const float4 rp2 = *(const float4*)(src + base + 2 * WW + j);
    const float4 rr  = *(const float4*)(rhs + base + j);

    // horizontal halo: cols j-2,j-1 and j+4,j+5 (8B aligned float2 loads).
    // At the row ends the halo values feed only boundary (copied) points, so
    // skipping the OOB load is safe.
    float2 cm = make_float2(0.0f, 0.0f);
    float2 cp = make_float2(0.0f, 0.0f);
    if (j >= 2)       cm = *(const float2*)(src + base + j - 2);
    if (j + 6 <= WW)  cp = *(const float2*)(src + base + j + 4);

    const float a_m2[4] = {rm2.x, rm2.y, rm2.z, rm2.w};
    const float a_m1[4] = {rm1.x, rm1.y, rm1.z, rm1.w};
    const float a_p1[4] = {rp1.x, rp1.y, rp1.z, rp1.w};
    const float a_p2[4] = {rp2.x, rp2.y, rp2.z, rp2.w};
    const float cen[4]  = {c4.x, c4.y, c4.z, c4.w};
    const float rv[4]   = {rr.x, rr.y, rr.z, rr.w};
    // row window cols j-2 .. j+5 ; cc[m] = col j-2+m
    const float cc[8] = {cm.x, cm.y, c4.x, c4.y, c4.z, c4.w, cp.x, cp.y};

    float o[4];
#pragma unroll
    for (int k = 0; k < 4; ++k) {
        const float cr = cH2 * (a_m2[k] + a_p2[k]) + cH1 * (a_m1[k] + a_p1[k])
                       + cW2 * (cc[k] + cc[k + 4]) + cW1 * (cc[k + 1] + cc[k + 3]);
        const float v = d_inv * (rv[k] - cr);
        const int col = j + k;
        o[k] = (col >= 2 && col < WW - 2) ? v : cen[k];
    }
    *(float4*)(dst + base + j) = make_float4(o[0], o[1], o[2], o[3]);
}

extern "C" void kernel_launch(void* const* d_in, const int* in_sizes, int n_in,
                              void* d_out, int out_size, void* d_ws, size_t ws_size,
                              hipStream_t stream) {
    const float* rhs = (const float*)d_in[1];
    const float* dx  = (const float*)d_in[2];
    float* g   = (float*)d_in[0];  // harness restores d_in before every timed
                                   // launch, so d_in[0] is legal ping-pong scratch
    float* out = (float*)d_out;

    dim3 grid(HH, NB), block(256);
    // 5 iterations, ping-pong so the final result lands in d_out.
    jacobi_step<<<grid, block, 0, stream>>>(g,   rhs, dx, out);
    jacobi_step<<<grid, block, 0, stream>>>(out, rhs, dx, g);
    jacobi_step<<<grid, block, 0, stream>>>(g,   rhs, dx, out);
    jacobi_step<<<grid, block, 0, stream>>>(out, rhs, dx, g);
    jacobi_step<<<grid, block, 0, stream>>>(g,   rhs, dx, out);
}

// Round 2
// 289.577 us; speedup vs baseline: 1.5242x; 1.5242x over previous
//
#include <hip/hip_runtime.h>

// Fused 5-iteration Jacobi, cross-stencil (5-pt FD 2nd derivative per axis),
// B=16, H=W=1024 fp32. Temporal tiling: halo 12 (>=10 needed, 12 keeps float4
// alignment), 88x88 LDS tile -> 5 in-LDS sweeps over shrinking region -> store
// central 64x64. Frozen boundary ring (width 2) handled by per-point global
// interior mask (masked points copy previous value).

#define HH 1024
#define WW 1024
#define NB 16
#define TILE 64
#define HALO 12
#define TW (TILE + 2 * HALO)   // 88
#define NG (TW / 4)            // 22 float4 col-groups per row
#define NITER 5

__device__ __forceinline__ void f4arr(const float4 v, float* a) {
    a[0] = v.x; a[1] = v.y; a[2] = v.z; a[3] = v.w;
}

__device__ __forceinline__ float4 row_update(
    const float4 a2, const float4 a1, const float4 ct, const float4 b1, const float4 b2,
    const float2 hm, const float2 hp, const float4 rv,
    const float sH1, const float sH2, const float sW1, const float sW2, const float d_inv,
    const int gy, const int gx0, const int c, const int lo, const int hi)
{
    float A2[4], A1[4], CT[4], B1[4], B2[4], RV[4];
    f4arr(a2, A2); f4arr(a1, A1); f4arr(ct, CT);
    f4arr(b1, B1); f4arr(b2, B2); f4arr(rv, RV);
    const float cc[8] = {hm.x, hm.y, CT[0], CT[1], CT[2], CT[3], hp.x, hp.y};
    const bool rowok = (gy >= 2) && (gy < HH - 2);
    float o[4];
#pragma unroll
    for (int kk = 0; kk < 4; ++kk) {
        float val = d_inv * RV[kk];
        val += sH2 * (A2[kk] + B2[kk]);          // rows +-2
        val += sH1 * (A1[kk] + B1[kk]);          // rows +-1
        val += sW2 * (cc[kk] + cc[kk + 4]);      // cols +-2
        val += sW1 * (cc[kk + 1] + cc[kk + 3]);  // cols +-1
        const int gx = gx0 + kk;
        const int lx = c + kk;
        const bool ok = rowok && (gx >= 2) && (gx < WW - 2) && (lx >= lo) && (lx < hi);
        o[kk] = ok ? val : CT[kk];
    }
    return make_float4(o[0], o[1], o[2], o[3]);
}

__global__ __launch_bounds__(256, 2) void jacobi_fused(
    const float* __restrict__ g0, const float* __restrict__ rhs,
    const float* __restrict__ dx, float* __restrict__ out)
{
    __shared__ __align__(16) float bufA[TW * TW];
    __shared__ __align__(16) float bufB[TW * TW];

    const int tid = (int)threadIdx.x;
    const int tx = (int)blockIdx.x, ty = (int)blockIdx.y, b = (int)blockIdx.z;
    const int x0 = tx * TILE, y0 = ty * TILE;

    const float* gb = g0 + (size_t)b * HH * WW;
    const float* rb = rhs + (size_t)b * HH * WW;
    float* ob = out + (size_t)b * HH * WW;

    // per-batch coefficients (d_inv folded in; note sign flip for the -cr term)
    const float t0 = 1.0f / dx[2 * b + 0], t1 = 1.0f / dx[2 * b + 1];
    const float p0 = t0 * t0, p1 = t1 * t1;
    const float d_inv = 1.0f / (-2.5f * (p0 + p1));
    const float sH1 = -d_inv * (4.0f / 3.0f) * p0;
    const float sH2 = -d_inv * (-1.0f / 12.0f) * p0;
    const float sW1 = -d_inv * (4.0f / 3.0f) * p1;
    const float sW2 = -d_inv * (-1.0f / 12.0f) * p1;

    // ---- load 88x88 input tile (clamped replicate; clamped slots never feed
    //      a stored point's chain) ----
    for (int t = tid; t < TW * NG; t += 256) {
        const int ly = t / NG;
        const int c = (t - ly * NG) * 4;
        int gy = y0 - HALO + ly;
        gy = gy < 0 ? 0 : (gy > HH - 1 ? HH - 1 : gy);
        const int gx0 = x0 - HALO + c;
        const float* row = gb + (size_t)gy * WW;
        float4 v;
        if (gx0 >= 0 && gx0 <= WW - 4) {
            v = *(const float4*)(row + gx0);
        } else {
            int xa = gx0 + 0; xa = xa < 0 ? 0 : (xa > WW - 1 ? WW - 1 : xa);
            int xb = gx0 + 1; xb = xb < 0 ? 0 : (xb > WW - 1 ? WW - 1 : xb);
            int xc = gx0 + 2; xc = xc < 0 ? 0 : (xc > WW - 1 ? WW - 1 : xc);
            int xd = gx0 + 3; xd = xd < 0 ? 0 : (xd > WW - 1 ? WW - 1 : xd);
            v = make_float4(row[xa], row[xb], row[xc], row[xd]);
        }
        *(float4*)(&bufA[ly * TW + c]) = v;
    }
    __syncthreads();

    float* src = bufA;
    float* dst = bufB;

    // ---- 5 fused sweeps over shrinking region [2k, TW-2k) ----
    for (int k = 1; k <= NITER; ++k) {
        const int lo = 2 * k, hi = TW - 2 * k;
        const int nitems = ((hi - lo) >> 1) * NG;  // 2 rows per work item
        for (int t = tid; t < nitems; t += 256) {
            const int rp = t / NG;
            const int c = (t - rp * NG) * 4;
            const int r = lo + 2 * rp;
            const float* s = src + r * TW + c;

            const float4 vm2 = *(const float4*)(s - 2 * TW);
            const float4 vm1 = *(const float4*)(s - TW);
            const float4 v0  = *(const float4*)(s);
            const float4 vp1 = *(const float4*)(s + TW);
            const float4 vp2 = *(const float4*)(s + 2 * TW);
            const float4 vp3 = *(const float4*)(s + 3 * TW);
            const float2 h0m = *(const float2*)(s - 2);
            const float2 h0p = *(const float2*)(s + 4);
            const float2 h1m = *(const float2*)(s + TW - 2);
            const float2 h1p = *(const float2*)(s + TW + 4);

            const int gx0 = x0 - HALO + c;
            const int gy0 = y0 - HALO + r;
            int gxc = gx0 < 0 ? 0 : (gx0 > WW - 4 ? WW - 4 : gx0);
            int gyc0 = gy0 < 0 ? 0 : (gy0 > HH - 1 ? HH - 1 : gy0);
            int gyc1 = gy0 + 1 < 0 ? 0 : (gy0 + 1 > HH - 1 ? HH - 1 : gy0 + 1);
            const float4 rr0 = *(const float4*)(rb + (size_t)gyc0 * WW + gxc);
            const float4 rr1 = *(const float4*)(rb + (size_t)gyc1 * WW + gxc);

            const float4 o0 = row_update(vm2, vm1, v0, vp1, vp2, h0m, h0p, rr0,
                                         sH1, sH2, sW1, sW2, d_inv,
                                         gy0, gx0, c, lo, hi);
            const float4 o1 = row_update(vm1, v0, vp1, vp2, vp3, h1m, h1p, rr1,
                                         sH1, sH2, sW1, sW2, d_inv,
                                         gy0 + 1, gx0, c, lo, hi);
            *(float4*)(dst + r * TW + c) = o0;
            *(float4*)(dst + (r + 1) * TW + c) = o1;
        }
        __syncthreads();
        float* tm = src; src = dst; dst = tm;
    }

    // ---- store central 64x64 ----
    for (int t = tid; t < TILE * (TILE / 4); t += 256) {
        const int rr = t / (TILE / 4);
        const int c4 = (t - rr * (TILE / 4)) * 4;
        const float4 v = *(const float4*)(src + (HALO + rr) * TW + HALO + c4);
        *(float4*)(ob + (size_t)(y0 + rr) * WW + x0 + c4) = v;
    }
}

extern "C" void kernel_launch(void* const* d_in, const int* in_sizes, int n_in,
                              void* d_out, int out_size, void* d_ws, size_t ws_size,
                              hipStream_t stream) {
    const float* g0  = (const float*)d_in[0];
    const float* rhs = (const float*)d_in[1];
    const float* dx  = (const float*)d_in[2];
    float* out = (float*)d_out;

    dim3 grid(WW / TILE, HH / TILE, NB), block(256);
    jacobi_fused<<<grid, block, 0, stream>>>(g0, rhs, dx, out);
}

// Round 3
// 222.540 us; speedup vs baseline: 1.9834x; 1.3012x over previous
//
#include <hip/hip_runtime.h>

// Fused 5-iteration Jacobi, cross-stencil, B=16, H=W=1024 fp32.
// Temporal tiling: 88x88 tile (halo 12 >= 10 needed, float4-aligned),
// LDS ping-pong, 5 in-LDS sweeps, store central 64x64.
// R3 changes vs R2:
//  - LDS row stride padded 88->92 floats (group stride 23, odd -> no b128 bank conflicts)
//  - 512 threads/block (16 waves/CU at 2 blocks/CU) for latency hiding
//  - fixed work assignment: 1 item = 4 rows x float4; rhs*d_inv cached in 16 regs
//  - full-region recompute (no shrinking-window mask; garbage provably confined
//    outside the valid window, final store [12,76) within window [10,78))
//  - interior blocks (76.6%) take a template fast path with zero masking

#define HH 1024
#define WW 1024
#define NB 16
#define TILE 64
#define HALO 12
#define TW (TILE + 2 * HALO)   // 88 rows / cols used
#define SW 92                  // padded LDS row stride (floats)
#define NG 22                  // float4 col-groups used per row
#define NITER 5
#define NTHREADS 512
#define NROWQ 21               // row quads covering rows [2,86)
#define NITEMS (NROWQ * NG)    // 462 work items per sweep

struct Coef { float sH1, sH2, sW1, sW2; };

template <bool EDGE>
__device__ __forceinline__ float4 upd_row(
    const float4 a2, const float4 a1, const float4 ct, const float4 b1, const float4 b2,
    const float2 hm, const float2 hp, const float4 rv, const Coef cf,
    const int gy, const int gx0)
{
    const float A2[4] = {a2.x, a2.y, a2.z, a2.w};
    const float A1[4] = {a1.x, a1.y, a1.z, a1.w};
    const float CT[4] = {ct.x, ct.y, ct.z, ct.w};
    const float B1[4] = {b1.x, b1.y, b1.z, b1.w};
    const float B2[4] = {b2.x, b2.y, b2.z, b2.w};
    const float RV[4] = {rv.x, rv.y, rv.z, rv.w};
    const float cc[8] = {hm.x, hm.y, ct.x, ct.y, ct.z, ct.w, hp.x, hp.y};
    const bool rowok = (gy >= 2) && (gy < HH - 2);
    float o[4];
#pragma unroll
    for (int k = 0; k < 4; ++k) {
        float v = RV[k];
        v = fmaf(cf.sH2, A2[k] + B2[k], v);
        v = fmaf(cf.sH1, A1[k] + B1[k], v);
        v = fmaf(cf.sW2, cc[k] + cc[k + 4], v);
        v = fmaf(cf.sW1, cc[k + 1] + cc[k + 3], v);
        if (EDGE) {
            const int gx = gx0 + k;
            const bool ok = rowok && (gx >= 2) && (gx < WW - 2);
            v = ok ? v : CT[k];
        }
        o[k] = v;
    }
    return make_float4(o[0], o[1], o[2], o[3]);
}

template <bool EDGE>
__device__ __forceinline__ void do_sweeps(
    float* src, float* dst, const bool active, const int r, const int c,
    const int gx0, const int gy0, const float4* rv, const Coef cf)
{
#pragma unroll
    for (int it = 0; it < NITER; ++it) {
        if (active) {
            const float* s = src + r * SW + c;
            const float4 f0 = *(const float4*)(s - 2 * SW);
            const float4 f1 = *(const float4*)(s - 1 * SW);
            const float4 f2 = *(const float4*)(s);
            const float4 f3 = *(const float4*)(s + 1 * SW);
            const float4 f4 = *(const float4*)(s + 2 * SW);
            const float4 f5 = *(const float4*)(s + 3 * SW);
            const float4 f6 = *(const float4*)(s + 4 * SW);
            const float4 f7 = *(const float4*)(s + 5 * SW);
            const float2 h0m = *(const float2*)(s - 2);
            const float2 h0p = *(const float2*)(s + 4);
            const float2 h1m = *(const float2*)(s + SW - 2);
            const float2 h1p = *(const float2*)(s + SW + 4);
            const float2 h2m = *(const float2*)(s + 2 * SW - 2);
            const float2 h2p = *(const float2*)(s + 2 * SW + 4);
            const float2 h3m = *(const float2*)(s + 3 * SW - 2);
            const float2 h3p = *(const float2*)(s + 3 * SW + 4);

            const float4 o0 = upd_row<EDGE>(f0, f1, f2, f3, f4, h0m, h0p, rv[0], cf, gy0 + 0, gx0);
            const float4 o1 = upd_row<EDGE>(f1, f2, f3, f4, f5, h1m, h1p, rv[1], cf, gy0 + 1, gx0);
            const float4 o2 = upd_row<EDGE>(f2, f3, f4, f5, f6, h2m, h2p, rv[2], cf, gy0 + 2, gx0);
            const float4 o3 = upd_row<EDGE>(f3, f4, f5, f6, f7, h3m, h3p, rv[3], cf, gy0 + 3, gx0);

            float* d = dst + r * SW + c;
            *(float4*)(d)            = o0;
            *(float4*)(d + 1 * SW)   = o1;
            *(float4*)(d + 2 * SW)   = o2;
            *(float4*)(d + 3 * SW)   = o3;
        }
        __syncthreads();
        float* tm = src; src = dst; dst = tm;
    }
}

__global__ __launch_bounds__(NTHREADS, 4) void jacobi_fused(
    const float* __restrict__ g0, const float* __restrict__ rhs,
    const float* __restrict__ dx, float* __restrict__ out)
{
    __shared__ __align__(16) float bufA[TW * SW];   // 32384 B
    __shared__ __align__(16) float bufB[TW * SW];   // total 64768 B

    const int tid = (int)threadIdx.x;
    const int tx = (int)blockIdx.x, ty = (int)blockIdx.y, b = (int)blockIdx.z;
    const int x0 = tx * TILE, y0 = ty * TILE;

    const float* gb = g0 + (size_t)b * HH * WW;
    const float* rb = rhs + (size_t)b * HH * WW;
    float* ob = out + (size_t)b * HH * WW;

    // per-batch coefficients (d_inv and the -cr sign folded in)
    const float t0 = 1.0f / dx[2 * b + 0], t1 = 1.0f / dx[2 * b + 1];
    const float p0 = t0 * t0, p1 = t1 * t1;
    const float d_inv = 1.0f / (-2.5f * (p0 + p1));
    Coef cf;
    cf.sH1 = -d_inv * (4.0f / 3.0f) * p0;
    cf.sH2 = -d_inv * (-1.0f / 12.0f) * p0;
    cf.sW1 = -d_inv * (4.0f / 3.0f) * p1;
    cf.sW2 = -d_inv * (-1.0f / 12.0f) * p1;

    // ---- per-thread fixed work item: 4 rows x 4 cols ----
    const bool active = tid < NITEMS;
    const int q = tid / NG;
    const int cg = tid - q * NG;
    const int r = 2 + 4 * q;       // rows r..r+3, r in [2,82]
    const int c = 4 * cg;          // cols c..c+3, c in [0,84]
    const int gx0 = x0 - HALO + c;
    const int gy0 = y0 - HALO + r;

    // rhs * d_inv preload into registers (clamped; clamped lanes are masked/garbage-safe)
    float4 rv[4] = {};
    if (active) {
        int gxc = gx0 < 0 ? 0 : (gx0 > WW - 4 ? WW - 4 : gx0);
#pragma unroll
        for (int j = 0; j < 4; ++j) {
            int gy = gy0 + j;
            gy = gy < 0 ? 0 : (gy > HH - 1 ? HH - 1 : gy);
            float4 v = *(const float4*)(rb + (size_t)gy * WW + gxc);
            rv[j] = make_float4(d_inv * v.x, d_inv * v.y, d_inv * v.z, d_inv * v.w);
        }
    }

    // ---- load 88x88 input tile into bufA (clamp-replicate at domain edges) ----
    for (int t = tid; t < TW * NG; t += NTHREADS) {
        const int ly = t / NG;
        const int c4 = (t - ly * NG) * 4;
        int gy = y0 - HALO + ly;
        gy = gy < 0 ? 0 : (gy > HH - 1 ? HH - 1 : gy);
        const int gxl = x0 - HALO + c4;
        const float* row = gb + (size_t)gy * WW;
        float4 v;
        if (gxl >= 0 && gxl <= WW - 4) {
            v = *(const float4*)(row + gxl);
        } else {
            int xa = gxl + 0; xa = xa < 0 ? 0 : (xa > WW - 1 ? WW - 1 : xa);
            int xb = gxl + 1; xb = xb < 0 ? 0 : (xb > WW - 1 ? WW - 1 : xb);
            int xc = gxl + 2; xc = xc < 0 ? 0 : (xc > WW - 1 ? WW - 1 : xc);
            int xd = gxl + 3; xd = xd < 0 ? 0 : (xd > WW - 1 ? WW - 1 : xd);
            v = make_float4(row[xa], row[xb], row[xc], row[xd]);
        }
        *(float4*)(&bufA[ly * SW + c4]) = v;
    }
    // zero the 4 padding cols of both buffers (keeps garbage finite/deterministic)
    for (int t = tid; t < TW; t += NTHREADS) {
        *(float4*)(&bufA[t * SW + 88]) = make_float4(0.f, 0.f, 0.f, 0.f);
        *(float4*)(&bufB[t * SW + 88]) = make_float4(0.f, 0.f, 0.f, 0.f);
    }
    __syncthreads();

    // interior fast path: tile + full halo strictly inside the frozen ring
    const bool interior = (x0 - HALO >= 2) && (x0 + TILE + HALO <= WW - 2) &&
                          (y0 - HALO >= 2) && (y0 + TILE + HALO <= HH - 2);
    if (interior) do_sweeps<false>(bufA, bufB, active, r, c, gx0, gy0, rv, cf);
    else          do_sweeps<true >(bufA, bufB, active, r, c, gx0, gy0, rv, cf);

    // ---- store central 64x64 (NITER=5 odd -> final data in bufB) ----
    for (int t = tid; t < TILE * (TILE / 4); t += NTHREADS) {
        const int rr = t / (TILE / 4);
        const int c4 = (t - rr * (TILE / 4)) * 4;
        const float4 v = *(const float4*)(&bufB[(HALO + rr) * SW + HALO + c4]);
        *(float4*)(ob + (size_t)(y0 + rr) * WW + x0 + c4) = v;
    }
}

extern "C" void kernel_launch(void* const* d_in, const int* in_sizes, int n_in,
                              void* d_out, int out_size, void* d_ws, size_t ws_size,
                              hipStream_t stream) {
    const float* g0  = (const float*)d_in[0];
    const float* rhs = (const float*)d_in[1];
    const float* dx  = (const float*)d_in[2];
    float* out = (float*)d_out;

    dim3 grid(WW / TILE, HH / TILE, NB), block(NTHREADS);
    jacobi_fused<<<grid, block, 0, stream>>>(g0, rhs, dx, out);
}

// Round 4
// 220.554 us; speedup vs baseline: 2.0012x; 1.0090x over previous
//
#include <hip/hip_runtime.h>

// Fused 5-iteration Jacobi, cross-stencil, B=16, H=W=1024 fp32.
// R4: conflict-free LDS geometry. Row = 128 floats = 32 float4 groups = 32 lanes,
// row stride 128 floats (%32 banks == 0) -> every 8-lane phase of every
// ds_read_b128/ds_write_b128 tiles banks 0..31 exactly (zero conflicts).
// Tile: 128x64 floats in LDS (halo 12 >= 10 needed), output 104x40 per block,
// grid 10x26x16 (ragged right/bottom via clamped loads + guarded stores).
// 5 in-LDS ping-pong sweeps, full-region recompute (garbage stays outside the
// dependency cone of the stored 104x40 center), EDGE mask only on ring blocks.

#define HH 1024
#define WW 1024
#define NB 16
#define TX 104
#define TY 40
#define HALO 12
#define TWX 128            // LDS row width == stride (floats)
#define TWY 64             // TY + 2*HALO
#define NGX 32             // float4 groups per row
#define NITER 5
#define NTHREADS 512
#define NQ 15              // row quads covering rows [2,62)
#define NITEMS (NQ * NGX)  // 480

struct Coef { float sH1, sH2, sW1, sW2; };

template <bool EDGE>
__device__ __forceinline__ float4 upd_row(
    const float4 a2, const float4 a1, const float4 ct, const float4 b1, const float4 b2,
    const float2 hm, const float2 hp, const float4 rv, const Coef cf,
    const int gy, const int gx0)
{
    const float A2[4] = {a2.x, a2.y, a2.z, a2.w};
    const float A1[4] = {a1.x, a1.y, a1.z, a1.w};
    const float CT[4] = {ct.x, ct.y, ct.z, ct.w};
    const float B1[4] = {b1.x, b1.y, b1.z, b1.w};
    const float B2[4] = {b2.x, b2.y, b2.z, b2.w};
    const float RV[4] = {rv.x, rv.y, rv.z, rv.w};
    const float cc[8] = {hm.x, hm.y, ct.x, ct.y, ct.z, ct.w, hp.x, hp.y};
    const bool rowok = (gy >= 2) && (gy < HH - 2);
    float o[4];
#pragma unroll
    for (int k = 0; k < 4; ++k) {
        float v = RV[k];
        v = fmaf(cf.sH2, A2[k] + B2[k], v);
        v = fmaf(cf.sH1, A1[k] + B1[k], v);
        v = fmaf(cf.sW2, cc[k] + cc[k + 4], v);
        v = fmaf(cf.sW1, cc[k + 1] + cc[k + 3], v);
        if (EDGE) {
            const int gx = gx0 + k;
            const bool ok = rowok && (gx >= 2) && (gx < WW - 2);
            v = ok ? v : CT[k];
        }
        o[k] = v;
    }
    return make_float4(o[0], o[1], o[2], o[3]);
}

template <bool EDGE>
__device__ __forceinline__ void do_sweeps(
    float* src, float* dst, const bool active, const int r, const int c,
    const int gx0, const int gy0, const float4* rv, const Coef cf)
{
#pragma unroll
    for (int it = 0; it < NITER; ++it) {
        if (active) {
            const float* s = src + r * TWX + c;
            const float4 f0 = *(const float4*)(s - 2 * TWX);
            const float4 f1 = *(const float4*)(s - 1 * TWX);
            const float4 f2 = *(const float4*)(s);
            const float4 f3 = *(const float4*)(s + 1 * TWX);
            const float4 f4 = *(const float4*)(s + 2 * TWX);
            const float4 f5 = *(const float4*)(s + 3 * TWX);
            const float4 f6 = *(const float4*)(s + 4 * TWX);
            const float4 f7 = *(const float4*)(s + 5 * TWX);
            const float2 h0m = *(const float2*)(s - 2);
            const float2 h0p = *(const float2*)(s + 4);
            const float2 h1m = *(const float2*)(s + TWX - 2);
            const float2 h1p = *(const float2*)(s + TWX + 4);
            const float2 h2m = *(const float2*)(s + 2 * TWX - 2);
            const float2 h2p = *(const float2*)(s + 2 * TWX + 4);
            const float2 h3m = *(const float2*)(s + 3 * TWX - 2);
            const float2 h3p = *(const float2*)(s + 3 * TWX + 4);

            const float4 o0 = upd_row<EDGE>(f0, f1, f2, f3, f4, h0m, h0p, rv[0], cf, gy0 + 0, gx0);
            const float4 o1 = upd_row<EDGE>(f1, f2, f3, f4, f5, h1m, h1p, rv[1], cf, gy0 + 1, gx0);
            const float4 o2 = upd_row<EDGE>(f2, f3, f4, f5, f6, h2m, h2p, rv[2], cf, gy0 + 2, gx0);
            const float4 o3 = upd_row<EDGE>(f3, f4, f5, f6, f7, h3m, h3p, rv[3], cf, gy0 + 3, gx0);

            float* d = dst + r * TWX + c;
            *(float4*)(d)            = o0;
            *(float4*)(d + 1 * TWX) = o1;
            *(float4*)(d + 2 * TWX) = o2;
            *(float4*)(d + 3 * TWX) = o3;
        }
        __syncthreads();
        float* tm = src; src = dst; dst = tm;
    }
}

__global__ __launch_bounds__(NTHREADS, 4) void jacobi_fused(
    const float* __restrict__ g0, const float* __restrict__ rhs,
    const float* __restrict__ dx, float* __restrict__ out)
{
    __shared__ __align__(16) float bufA[TWY * TWX];   // 32 KiB
    __shared__ __align__(16) float bufB[TWY * TWX];   // 64 KiB total -> 2 blocks/CU

    const int tid = (int)threadIdx.x;
    const int tx = (int)blockIdx.x, ty = (int)blockIdx.y, b = (int)blockIdx.z;
    const int x0 = tx * TX, y0 = ty * TY;

    const float* gb = g0 + (size_t)b * HH * WW;
    const float* rb = rhs + (size_t)b * HH * WW;
    float* ob = out + (size_t)b * HH * WW;

    // per-batch coefficients (d_inv and the -cr sign folded in)
    const float t0 = 1.0f / dx[2 * b + 0], t1 = 1.0f / dx[2 * b + 1];
    const float p0 = t0 * t0, p1 = t1 * t1;
    const float d_inv = 1.0f / (-2.5f * (p0 + p1));
    Coef cf;
    cf.sH1 = -d_inv * (4.0f / 3.0f) * p0;
    cf.sH2 = -d_inv * (-1.0f / 12.0f) * p0;
    cf.sW1 = -d_inv * (4.0f / 3.0f) * p1;
    cf.sW2 = -d_inv * (-1.0f / 12.0f) * p1;

    // ---- fixed work item: 4 rows x 4 cols; lane%32 == col group -> b128 phases
    //      are 32-bank aligned ----
    const bool active = tid < NITEMS;
    const int q = tid >> 5;            // row quad 0..14
    const int cg = tid & 31;           // col group 0..31
    const int r = 2 + 4 * q;           // rows r..r+3 in [2,62)
    const int c = 4 * cg;              // cols c..c+3 in [0,128)
    const int gx0 = x0 - HALO + c;
    const int gy0 = y0 - HALO + r;

    // rhs * d_inv preload (clamped; clamped lanes only feed masked/garbage points)
    float4 rv[4] = {};
    if (active) {
        int gxc = gx0 < 0 ? 0 : (gx0 > WW - 4 ? WW - 4 : gx0);
#pragma unroll
        for (int j = 0; j < 4; ++j) {
            int gy = gy0 + j;
            gy = gy < 0 ? 0 : (gy > HH - 1 ? HH - 1 : gy);
            float4 v = *(const float4*)(rb + (size_t)gy * WW + gxc);
            rv[j] = make_float4(d_inv * v.x, d_inv * v.y, d_inv * v.z, d_inv * v.w);
        }
    }

    // ---- load 128x64 input tile into bufA (clamp-replicate at domain edges) ----
#pragma unroll
    for (int tt = 0; tt < (TWY * NGX) / NTHREADS; ++tt) {
        const int t = tid + tt * NTHREADS;
        const int ly = t >> 5;
        const int c4 = (t & 31) * 4;
        int gy = y0 - HALO + ly;
        gy = gy < 0 ? 0 : (gy > HH - 1 ? HH - 1 : gy);
        const int gxl = x0 - HALO + c4;
        const float* row = gb + (size_t)gy * WW;
        float4 v;
        if (gxl >= 0 && gxl <= WW - 4) {
            v = *(const float4*)(row + gxl);
        } else {
            int xa = gxl + 0; xa = xa < 0 ? 0 : (xa > WW - 1 ? WW - 1 : xa);
            int xb = gxl + 1; xb = xb < 0 ? 0 : (xb > WW - 1 ? WW - 1 : xb);
            int xc = gxl + 2; xc = xc < 0 ? 0 : (xc > WW - 1 ? WW - 1 : xc);
            int xd = gxl + 3; xd = xd < 0 ? 0 : (xd > WW - 1 ? WW - 1 : xd);
            v = make_float4(row[xa], row[xb], row[xc], row[xd]);
        }
        *(float4*)(&bufA[ly * TWX + c4]) = v;
    }
    __syncthreads();

    // interior fast path (conservative: dependency cone of the stored center
    // strictly inside the frozen ring)
    const bool interior = (x0 - HALO >= 2) && (x0 + TX + HALO <= WW - 2) &&
                          (y0 - HALO >= 2) && (y0 + TY + HALO <= HH - 2);
    if (interior) do_sweeps<false>(bufA, bufB, active, r, c, gx0, gy0, rv, cf);
    else          do_sweeps<true >(bufA, bufB, active, r, c, gx0, gy0, rv, cf);

    // ---- store center: LDS cols [12,116) rows [12,52) -> global 104x40
    //      (guarded for ragged right/bottom tiles); NITER=5 odd -> data in bufB ----
    for (int t = tid; t < TY * (TX / 4); t += NTHREADS) {
        const int rr = t / (TX / 4);
        const int k4 = (t - rr * (TX / 4)) * 4;
        const int gx = x0 + k4;
        const int gy = y0 + rr;
        if (gy < HH && gx <= WW - 4) {
            const float4 v = *(const float4*)(&bufB[(HALO + rr) * TWX + HALO + k4]);
            *(float4*)(ob + (size_t)gy * WW + gx) = v;
        }
    }
}

extern "C" void kernel_launch(void* const* d_in, const int* in_sizes, int n_in,
                              void* d_out, int out_size, void* d_ws, size_t ws_size,
                              hipStream_t stream) {
    const float* g0  = (const float*)d_in[0];
    const float* rhs = (const float*)d_in[1];
    const float* dx  = (const float*)d_in[2];
    float* out = (float*)d_out;

    dim3 grid((WW + TX - 1) / TX, (HH + TY - 1) / TY, NB), block(NTHREADS);
    jacobi_fused<<<grid, block, 0, stream>>>(g0, rhs, dx, out);
}